// Round 10
// baseline (1985.559 us; speedup 1.0000x reference)
//
#include <hip/hip_runtime.h>
#include <hip/hip_bf16.h>

// MoE block: H=2048, F=8192, E=8, top-2, T=512 tokens. All inputs fp32.
// Round 10: NO global_load_lds anywhere. Weights staged global->VGPR->LDS
// (reg-staging / T14): plain global_load_dwordx4, ds_write_b128, with loads
// for kt+1 issued immediately after the ds_writes of kt. All vmem waits are
// compiler-inserted on register use; manual sync is only lgkmcnt(0) +
// raw s_barrier (+ sched_barrier pins). Probes whether the LDS-DMA path
// was the 2.2 TB/s limiter. Geometry = r8-proven BM=128 BN=64 BK=32.

#define HDIM 2048
#define FDIM 8192
#define NEXP 8
#define NTOK 512
#define MAXT 512

typedef __attribute__((ext_vector_type(8))) short short8;
typedef __attribute__((ext_vector_type(4))) float f32x4;
typedef unsigned int u32;
typedef unsigned short u16;

__device__ __forceinline__ unsigned cvtpk(float lo, float hi) {
    unsigned r;
    asm("v_cvt_pk_bf16_f32 %0, %1, %2" : "=v"(r) : "v"(lo), "v"(hi));
    return r;
}
__device__ __forceinline__ unsigned f2bf1(float f) {
    unsigned u = __builtin_bit_cast(unsigned, f);
    return (u + 0x7FFFu + ((u >> 16) & 1u)) >> 16;
}
#define SBAR() __builtin_amdgcn_sched_barrier(0)

// ---------------------------------------------------------------- router
__global__ void moe_router(const float* __restrict__ x, const float* __restrict__ Wg,
                           int* __restrict__ counts, int* __restrict__ tok_id,
                           float* __restrict__ tok_w) {
    const int t = blockIdx.x;
    const int lane = threadIdx.x;
    const float* xr = x + (size_t)t * HDIM;
    float acc[8];
    #pragma unroll
    for (int e = 0; e < 8; ++e) acc[e] = 0.f;
    #pragma unroll 4
    for (int i = 0; i < HDIM / 64; ++i) {
        int h = lane + i * 64;
        float xv = xr[h];
        const float4* wr = (const float4*)(Wg + (size_t)h * 8);
        float4 wa = wr[0], wb = wr[1];
        acc[0] += xv * wa.x; acc[1] += xv * wa.y; acc[2] += xv * wa.z; acc[3] += xv * wa.w;
        acc[4] += xv * wb.x; acc[5] += xv * wb.y; acc[6] += xv * wb.z; acc[7] += xv * wb.w;
    }
    #pragma unroll
    for (int off = 32; off >= 1; off >>= 1) {
        #pragma unroll
        for (int e = 0; e < 8; ++e) acc[e] += __shfl_xor(acc[e], off);
    }
    if (lane == 0) {
        int e0 = 0;
        #pragma unroll
        for (int e = 1; e < 8; ++e) if (acc[e] > acc[e0]) e0 = e;
        int e1 = (e0 == 0) ? 1 : 0;
        #pragma unroll
        for (int e = 0; e < 8; ++e) if (e != e0 && acc[e] > acc[e1]) e1 = e;
        float w0 = 1.f / (1.f + __expf(acc[e1] - acc[e0]));
        float w1 = 1.f - w0;
        int s0 = atomicAdd(&counts[e0], 1);
        tok_id[e0 * MAXT + s0] = t; tok_w[e0 * MAXT + s0] = w0;
        int s1 = atomicAdd(&counts[e1], 1);
        tok_id[e1 * MAXT + s1] = t; tok_w[e1 * MAXT + s1] = w1;
    }
}

__global__ void moe_scan(const int* __restrict__ counts, int* __restrict__ offsets) {
    if (threadIdx.x == 0) {
        int a = 0;
        for (int e = 0; e < NEXP; ++e) { offsets[e] = a; a += counts[e]; }
    }
}

// ------------------------------------------------------------- x -> bf16
__global__ void moe_xcvt(const float* __restrict__ x, u16* __restrict__ xbf) {
    const int i = (blockIdx.x * 256 + threadIdx.x) * 8;
    float4 a = *(const float4*)(x + i);
    float4 b = *(const float4*)(x + i + 4);
    uint4 q;
    q.x = cvtpk(a.x, a.y); q.y = cvtpk(a.z, a.w);
    q.z = cvtpk(b.x, b.y); q.w = cvtpk(b.z, b.w);
    *(uint4*)(xbf + i) = q;
}

// B-fragment: weights fp32 in LDS as [32 k][64 n], dword col n' =
// n ^ (((k>>3)&1)<<4). 8x ds_read_b32 (2-way = free) + 4 cvt_pk. Verified.
__device__ __forceinline__ short8 bfrag(const float* sB, int kbase, int nsw) {
    const float* p = sB + kbase * 64 + nsw;
    float f[8];
    #pragma unroll
    for (int j = 0; j < 8; ++j) f[j] = p[j * 64];
    uint4 q;
    q.x = cvtpk(f[0], f[1]); q.y = cvtpk(f[2], f[3]);
    q.z = cvtpk(f[4], f[5]); q.w = cvtpk(f[6], f[7]);
    return __builtin_bit_cast(short8, q);
}

// ---------------------------------------------------------------- GEMM1
// h[slot,n] = relu(x W1) * (x W3), bf16 out. BM=128 BN=64 BK=32, waves 2x2.
// Reg-staged B (dbuf LDS), direct-to-reg A (dbuf regs).
__global__ __launch_bounds__(256, 3)
void moe_gemm1(const u16* __restrict__ xbf, const float* __restrict__ W1,
               const float* __restrict__ W3, const int* __restrict__ counts,
               const int* __restrict__ offsets, const int* __restrict__ tok_id,
               u16* __restrict__ hbuf) {
    const int nt = blockIdx.x, mt = blockIdx.y, e = blockIdx.z;
    const int cnt = counts[e];
    if (mt * 128 >= cnt) return;
    const int n0 = nt * 64;
    const int tid = threadIdx.x;
    const int w = tid >> 6, l = tid & 63;

    __shared__ __align__(16) float sB1[2][32 * 64];   // 8 KB each buf
    __shared__ __align__(16) float sB3[2][32 * 64];   // total 32 KB

    const int wr = (w >> 1) * 64, wc = (w & 1) * 32;
    const int lr = l & 15, lg = l >> 4;
    const int lk = lg * 8;
    const int g1 = lg & 1;

    // A fragment bases (r8-proven): lane covers row wr+mi*16+lr, k-chunk lg*8.
    const u16* abase[4];
    #pragma unroll
    for (int mi = 0; mi < 4; ++mi) {
        int slot = mt * 128 + wr + mi * 16 + lr;
        int tok = tok_id[e * MAXT + (slot < cnt ? slot : cnt - 1)];
        abase[mi] = xbf + (size_t)tok * HDIM + lk;
    }
    // B staging: thread covers k-row br = tid>>3 (0..31), dwords bc..bc+7.
    // LDS col = bc ^ (octet<<4) (content map identical to verified bfrag).
    const int br = tid >> 3, bc = (tid & 7) * 8;
    const int bcx = bc ^ (((br >> 3) & 1) << 4);
    const size_t wstride = (size_t)HDIM * FDIM;
    const float* b1s = W1 + (size_t)e * wstride + (size_t)br * FDIM + n0 + bc;
    const float* b3s = W3 + (size_t)e * wstride + (size_t)br * FDIM + n0 + bc;
    const int bldst = br * 64 + bcx;

    f32x4 acc1[4][2], acc3[4][2];
    #pragma unroll
    for (int mi = 0; mi < 4; ++mi)
        #pragma unroll
        for (int ni = 0; ni < 2; ++ni) { acc1[mi][ni] = (f32x4)0.f; acc3[mi][ni] = (f32x4)0.f; }

    float4 r1a, r1b, r3a, r3b;
    uint4 afA[4], afB[4];

    #define BLOAD1(kt) { const float* p1_ = b1s + (size_t)(kt) * 32 * FDIM;    \
                         r1a = *(const float4*)p1_;                            \
                         r1b = *(const float4*)(p1_ + 4);                      \
                         const float* p3_ = b3s + (size_t)(kt) * 32 * FDIM;    \
                         r3a = *(const float4*)p3_;                            \
                         r3b = *(const float4*)(p3_ + 4); }
    #define BWRITE1(buf) { *(float4*)&sB1[buf][bldst] = r1a;                   \
                           *(float4*)&sB1[buf][bldst + 4] = r1b;               \
                           *(float4*)&sB3[buf][bldst] = r3a;                   \
                           *(float4*)&sB3[buf][bldst + 4] = r3b; }
    #define AISSUE1(AF, kt)                                                    \
        _Pragma("unroll")                                                      \
        for (int mi = 0; mi < 4; ++mi)                                         \
            AF[mi] = *(const uint4*)(abase[mi] + (size_t)(kt) * 32);
    #define MFMAP1(AF, buf)                                                    \
        _Pragma("unroll")                                                      \
        for (int ni = 0; ni < 2; ++ni) {                                       \
            const int nsw = (wc + ni * 16 + lr) ^ (g1 << 4);                   \
            short8 b1 = bfrag(sB1[buf], lk, nsw);                              \
            short8 b3 = bfrag(sB3[buf], lk, nsw);                              \
            _Pragma("unroll")                                                  \
            for (int mi = 0; mi < 4; ++mi) {                                   \
                short8 a_ = __builtin_bit_cast(short8, AF[mi]);                \
                acc1[mi][ni] = __builtin_amdgcn_mfma_f32_16x16x32_bf16(a_, b1, acc1[mi][ni], 0, 0, 0); \
                acc3[mi][ni] = __builtin_amdgcn_mfma_f32_16x16x32_bf16(a_, b3, acc3[mi][ni], 0, 0, 0); \
            }                                                                  \
        }

    BLOAD1(0);
    AISSUE1(afA, 0);
    for (int kt = 0; kt < HDIM / 32; ++kt) {
        const int cur = kt & 1;
        BWRITE1(cur);                          // compiler waits vmcnt for B(kt) regs
        if (kt + 1 < HDIM / 32) {
            BLOAD1(kt + 1);                    // refill staging regs (WAR safe: in-order issue)
            if (cur) { AISSUE1(afA, kt + 1); } else { AISSUE1(afB, kt + 1); }
        }
        asm volatile("s_waitcnt lgkmcnt(0)" ::: "memory");   // ds_writes visible
        SBAR();
        __builtin_amdgcn_s_barrier();
        SBAR();
        if (cur) { MFMAP1(afB, 1); } else { MFMAP1(afA, 0); }
        SBAR();
        __builtin_amdgcn_s_barrier();
        SBAR();
    }
    #undef BLOAD1
    #undef BWRITE1
    #undef AISSUE1
    #undef MFMAP1

    // ---- epilogue: h = relu(h1)*h3 -> bf16 compact rows
    const int hbase = offsets[e] + mt * 128;
    #pragma unroll
    for (int mi = 0; mi < 4; ++mi)
        #pragma unroll
        for (int ni = 0; ni < 2; ++ni)
            #pragma unroll
            for (int r = 0; r < 4; ++r) {
                int rl = wr + mi * 16 + (l >> 4) * 4 + r;
                int sl = mt * 128 + rl;
                if (sl < cnt) {
                    float v1 = acc1[mi][ni][r];
                    v1 = v1 > 0.f ? v1 : 0.f;
                    float hv = v1 * acc3[mi][ni][r];
                    hbuf[(size_t)(hbase + rl) * FDIM + (n0 + wc + ni * 16 + lr)] =
                        (u16)f2bf1(hv);
                }
            }
}

// ---------------------------------------------------------------- GEMM2
// out[t,n] += w * (h W2). BM=128 BN=64 BK=32, split-K x4. Reg-staged B.
__global__ __launch_bounds__(256, 4)
void moe_gemm2(const u16* __restrict__ hbuf, const float* __restrict__ W2,
               const int* __restrict__ counts, const int* __restrict__ offsets,
               const int* __restrict__ tok_id, const float* __restrict__ tok_w,
               float* __restrict__ out) {
    const int nt = blockIdx.x, e = blockIdx.z;
    const int mt = blockIdx.y & 3, ksp = blockIdx.y >> 2;
    const int cnt = counts[e];
    if (mt * 128 >= cnt) return;
    const int n0 = nt * 64;
    const int tid = threadIdx.x;
    const int w = tid >> 6, l = tid & 63;

    __shared__ __align__(16) float sB[2][32 * 64];   // 16 KB

    const int wr = (w >> 1) * 64, wc = (w & 1) * 32;
    const int lr = l & 15, lg = l >> 4;
    const int lk = lg * 8;
    const int g1 = lg & 1;

    const u16* abase[4];
    #pragma unroll
    for (int mi = 0; mi < 4; ++mi) {
        int hrow = offsets[e] + mt * 128 + wr + mi * 16 + lr;  // tail rows stale, masked below
        abase[mi] = hbuf + (size_t)hrow * FDIM + ksp * 2048 + lk;
    }
    const int br = tid >> 3, bc = (tid & 7) * 8;
    const int bcx = bc ^ (((br >> 3) & 1) << 4);
    const float* b2s = W2 + (size_t)e * ((size_t)FDIM * HDIM) +
                       (size_t)(ksp * 2048 + br) * HDIM + n0 + bc;
    const int bldst = br * 64 + bcx;

    f32x4 acc[4][2];
    #pragma unroll
    for (int mi = 0; mi < 4; ++mi)
        #pragma unroll
        for (int ni = 0; ni < 2; ++ni) acc[mi][ni] = (f32x4)0.f;

    float4 r2a, r2b;
    uint4 afA[4], afB[4];

    #define BLOAD2(kt) { const float* p_ = b2s + (size_t)(kt) * 32 * HDIM;     \
                         r2a = *(const float4*)p_;                             \
                         r2b = *(const float4*)(p_ + 4); }
    #define BWRITE2(buf) { *(float4*)&sB[buf][bldst] = r2a;                    \
                           *(float4*)&sB[buf][bldst + 4] = r2b; }
    #define AISSUE2(AF, kt)                                                    \
        _Pragma("unroll")                                                      \
        for (int mi = 0; mi < 4; ++mi)                                         \
            AF[mi] = *(const uint4*)(abase[mi] + (size_t)(kt) * 32);
    #define MFMAP2(AF, buf)                                                    \
        _Pragma("unroll")                                                      \
        for (int ni = 0; ni < 2; ++ni) {                                       \
            const int nsw = (wc + ni * 16 + lr) ^ (g1 << 4);                   \
            short8 b = bfrag(sB[buf], lk, nsw);                                \
            _Pragma("unroll")                                                  \
            for (int mi = 0; mi < 4; ++mi) {                                   \
                short8 a_ = __builtin_bit_cast(short8, AF[mi]);                \
                acc[mi][ni] = __builtin_amdgcn_mfma_f32_16x16x32_bf16(a_, b, acc[mi][ni], 0, 0, 0); \
            }                                                                  \
        }

    BLOAD2(0);
    AISSUE2(afA, 0);
    for (int kt = 0; kt < 64; ++kt) {
        const int cur = kt & 1;
        BWRITE2(cur);
        if (kt + 1 < 64) {
            BLOAD2(kt + 1);
            if (cur) { AISSUE2(afA, kt + 1); } else { AISSUE2(afB, kt + 1); }
        }
        asm volatile("s_waitcnt lgkmcnt(0)" ::: "memory");
        SBAR();
        __builtin_amdgcn_s_barrier();
        SBAR();
        if (cur) { MFMAP2(afB, 1); } else { MFMAP2(afA, 0); }
        SBAR();
        __builtin_amdgcn_s_barrier();
        SBAR();
    }
    #undef BLOAD2
    #undef BWRITE2
    #undef AISSUE2
    #undef MFMAP2

    // ---- epilogue: scaled partial scatter-add
    #pragma unroll
    for (int mi = 0; mi < 4; ++mi)
        #pragma unroll
        for (int ni = 0; ni < 2; ++ni)
            #pragma unroll
            for (int r = 0; r < 4; ++r) {
                int rl = wr + mi * 16 + (l >> 4) * 4 + r;
                int sl = mt * 128 + rl;
                if (sl < cnt) {
                    int tk = tok_id[e * MAXT + sl];
                    float wgt = tok_w[e * MAXT + sl];
                    atomicAdd(&out[(size_t)tk * HDIM + (n0 + wc + ni * 16 + lr)],
                              wgt * acc[mi][ni][r]);
                }
            }
}

// ---------------------------------------------------------------- launch
extern "C" void kernel_launch(void* const* d_in, const int* in_sizes, int n_in,
                              void* d_out, int out_size, void* d_ws, size_t ws_size,
                              hipStream_t stream) {
    const float* x  = (const float*)d_in[0];
    const float* Wg = (const float*)d_in[1];
    const float* W1 = (const float*)d_in[2];
    const float* W2 = (const float*)d_in[3];
    const float* W3 = (const float*)d_in[4];
    float* out = (float*)d_out;

    char* ws = (char*)d_ws;
    int*   counts  = (int*)(ws + 0);
    int*   offsets = (int*)(ws + 32);
    int*   tok_id  = (int*)(ws + 64);
    float* tok_w   = (float*)(ws + 64 + NEXP * MAXT * 4);
    u16*   xbf     = (u16*)(ws + 65536);                            // 512x2048 bf16 = 2MB
    u16*   hbuf    = (u16*)(ws + 65536 + (size_t)NTOK * HDIM * 2);  // (1024+128)x8192 bf16

    hipMemsetAsync(ws, 0, 64, stream);
    hipMemsetAsync(d_out, 0, (size_t)out_size * sizeof(float), stream);

    moe_router<<<NTOK, 64, 0, stream>>>(x, Wg, counts, tok_id, tok_w);
    moe_scan<<<1, 64, 0, stream>>>(counts, offsets);
    moe_xcvt<<<NTOK * HDIM / (256 * 8), 256, 0, stream>>>(x, xbf);
    moe_gemm1<<<dim3(FDIM / 64, 4, NEXP), 256, 0, stream>>>(xbf, W1, W3, counts, offsets, tok_id, hbuf);
    moe_gemm2<<<dim3(HDIM / 64, 16, NEXP), 256, 0, stream>>>(hbuf, W2, counts, offsets, tok_id, tok_w, out);
}

// Round 11
// 641.020 us; speedup vs baseline: 3.0975x; 3.0975x over previous
//
#include <hip/hip_runtime.h>
#include <hip/hip_bf16.h>

// MoE block: H=2048, F=8192, E=8, top-2, T=512 tokens. All inputs fp32.
// Round 11: r10's plain-load reg-staging (which broke the 2.2 TB/s DMA wall:
// 3.7 TB/s even while spilling) with spill-proof codegen: no branches, one
// staging register set, one A-fragment array (static indices), LDS buffer
// chosen by runtime POINTER. Compiler inserts all counted vmcnt waits from
// dataflow; manual sync = lgkmcnt(0) + raw s_barrier only.

#define HDIM 2048
#define FDIM 8192
#define NEXP 8
#define NTOK 512
#define MAXT 512

typedef __attribute__((ext_vector_type(8))) short short8;
typedef __attribute__((ext_vector_type(4))) float f32x4;
typedef unsigned int u32;
typedef unsigned short u16;

__device__ __forceinline__ unsigned cvtpk(float lo, float hi) {
    unsigned r;
    asm("v_cvt_pk_bf16_f32 %0, %1, %2" : "=v"(r) : "v"(lo), "v"(hi));
    return r;
}
__device__ __forceinline__ unsigned f2bf1(float f) {
    unsigned u = __builtin_bit_cast(unsigned, f);
    return (u + 0x7FFFu + ((u >> 16) & 1u)) >> 16;
}
#define SBAR() __builtin_amdgcn_sched_barrier(0)

// ---------------------------------------------------------------- router
__global__ void moe_router(const float* __restrict__ x, const float* __restrict__ Wg,
                           int* __restrict__ counts, int* __restrict__ tok_id,
                           float* __restrict__ tok_w) {
    const int t = blockIdx.x;
    const int lane = threadIdx.x;
    const float* xr = x + (size_t)t * HDIM;
    float acc[8];
    #pragma unroll
    for (int e = 0; e < 8; ++e) acc[e] = 0.f;
    #pragma unroll 4
    for (int i = 0; i < HDIM / 64; ++i) {
        int h = lane + i * 64;
        float xv = xr[h];
        const float4* wr = (const float4*)(Wg + (size_t)h * 8);
        float4 wa = wr[0], wb = wr[1];
        acc[0] += xv * wa.x; acc[1] += xv * wa.y; acc[2] += xv * wa.z; acc[3] += xv * wa.w;
        acc[4] += xv * wb.x; acc[5] += xv * wb.y; acc[6] += xv * wb.z; acc[7] += xv * wb.w;
    }
    #pragma unroll
    for (int off = 32; off >= 1; off >>= 1) {
        #pragma unroll
        for (int e = 0; e < 8; ++e) acc[e] += __shfl_xor(acc[e], off);
    }
    if (lane == 0) {
        int e0 = 0;
        #pragma unroll
        for (int e = 1; e < 8; ++e) if (acc[e] > acc[e0]) e0 = e;
        int e1 = (e0 == 0) ? 1 : 0;
        #pragma unroll
        for (int e = 0; e < 8; ++e) if (e != e0 && acc[e] > acc[e1]) e1 = e;
        float w0 = 1.f / (1.f + __expf(acc[e1] - acc[e0]));
        float w1 = 1.f - w0;
        int s0 = atomicAdd(&counts[e0], 1);
        tok_id[e0 * MAXT + s0] = t; tok_w[e0 * MAXT + s0] = w0;
        int s1 = atomicAdd(&counts[e1], 1);
        tok_id[e1 * MAXT + s1] = t; tok_w[e1 * MAXT + s1] = w1;
    }
}

__global__ void moe_scan(const int* __restrict__ counts, int* __restrict__ offsets) {
    if (threadIdx.x == 0) {
        int a = 0;
        for (int e = 0; e < NEXP; ++e) { offsets[e] = a; a += counts[e]; }
    }
}

// ------------------------------------------------------------- x -> bf16
__global__ void moe_xcvt(const float* __restrict__ x, u16* __restrict__ xbf) {
    const int i = (blockIdx.x * 256 + threadIdx.x) * 8;
    float4 a = *(const float4*)(x + i);
    float4 b = *(const float4*)(x + i + 4);
    uint4 q;
    q.x = cvtpk(a.x, a.y); q.y = cvtpk(a.z, a.w);
    q.z = cvtpk(b.x, b.y); q.w = cvtpk(b.z, b.w);
    *(uint4*)(xbf + i) = q;
}

// B-fragment: weights fp32 in LDS as [32 k][64 n], dword col n' =
// n ^ (((k>>3)&1)<<4). 8x ds_read_b32 (2-way = free) + 4 cvt_pk. Verified.
__device__ __forceinline__ short8 bfrag(const float* sB, int kbase, int nsw) {
    const float* p = sB + kbase * 64 + nsw;
    float f[8];
    #pragma unroll
    for (int j = 0; j < 8; ++j) f[j] = p[j * 64];
    uint4 q;
    q.x = cvtpk(f[0], f[1]); q.y = cvtpk(f[2], f[3]);
    q.z = cvtpk(f[4], f[5]); q.w = cvtpk(f[6], f[7]);
    return __builtin_bit_cast(short8, q);
}

// ---------------------------------------------------------------- GEMM1
// h[slot,n] = relu(x W1) * (x W3), bf16 out. BM=128 BN=64 BK=32, waves 2x2.
// Reg-staged B (dbuf LDS via pointer), single A-frag set per iteration.
__global__ __launch_bounds__(256, 2)
void moe_gemm1(const u16* __restrict__ xbf, const float* __restrict__ W1,
               const float* __restrict__ W3, const int* __restrict__ counts,
               const int* __restrict__ offsets, const int* __restrict__ tok_id,
               u16* __restrict__ hbuf) {
    const int nt = blockIdx.x, mt = blockIdx.y, e = blockIdx.z;
    const int cnt = counts[e];
    if (mt * 128 >= cnt) return;
    const int n0 = nt * 64;
    const int tid = threadIdx.x;
    const int w = tid >> 6, l = tid & 63;

    __shared__ __align__(16) float sB1[2][32 * 64];   // 16 KB
    __shared__ __align__(16) float sB3[2][32 * 64];   // 16 KB

    const int wr = (w >> 1) * 64, wc = (w & 1) * 32;
    const int lr = l & 15, lg = l >> 4;
    const int lk = lg * 8;
    const int g1 = lg & 1;

    // A fragment bases (r8-proven): lane covers row wr+mi*16+lr, k-chunk lg*8.
    const u16* abase[4];
    #pragma unroll
    for (int mi = 0; mi < 4; ++mi) {
        int slot = mt * 128 + wr + mi * 16 + lr;
        int tok = tok_id[e * MAXT + (slot < cnt ? slot : cnt - 1)];
        abase[mi] = xbf + (size_t)tok * HDIM + lk;
    }
    // B staging (r10-verified map): thread covers k-row br = tid>>3 (0..31),
    // dwords bc..bc+7; LDS col = bc ^ (octet<<4).
    const int br = tid >> 3, bc = (tid & 7) * 8;
    const int bcx = bc ^ (((br >> 3) & 1) << 4);
    const size_t wstride = (size_t)HDIM * FDIM;
    const float* b1s = W1 + (size_t)e * wstride + (size_t)br * FDIM + n0 + bc;
    const float* b3s = W3 + (size_t)e * wstride + (size_t)br * FDIM + n0 + bc;
    const int bldst = br * 64 + bcx;

    f32x4 acc1[4][2], acc3[4][2];
    #pragma unroll
    for (int mi = 0; mi < 4; ++mi)
        #pragma unroll
        for (int ni = 0; ni < 2; ++ni) { acc1[mi][ni] = (f32x4)0.f; acc3[mi][ni] = (f32x4)0.f; }

    float4 r1a, r1b, r3a, r3b;
    uint4 af[4];

    #define BLOAD1(kt) { const float* p1_ = b1s + (size_t)(kt) * 32 * FDIM;    \
                         r1a = *(const float4*)p1_;                            \
                         r1b = *(const float4*)(p1_ + 4);                      \
                         const float* p3_ = b3s + (size_t)(kt) * 32 * FDIM;    \
                         r3a = *(const float4*)p3_;                            \
                         r3b = *(const float4*)(p3_ + 4); }

    BLOAD1(0);
    for (int kt = 0; kt < HDIM / 32; ++kt) {
        float* s1c = sB1[kt & 1];
        float* s3c = sB3[kt & 1];
        // write staged regs for kt (compiler: vmcnt wait on B(kt) regs)
        *(float4*)&s1c[bldst] = r1a;  *(float4*)&s1c[bldst + 4] = r1b;
        *(float4*)&s3c[bldst] = r3a;  *(float4*)&s3c[bldst + 4] = r3b;
        SBAR();
        // issue A(kt) — L2-resident, retires before MFMA via counted wait
        #pragma unroll
        for (int mi = 0; mi < 4; ++mi)
            af[mi] = *(const uint4*)(abase[mi] + (size_t)kt * 32);
        SBAR();
        // issue B(kt+1) — stays in flight through the MFMA phase
        if (kt + 1 < HDIM / 32) BLOAD1(kt + 1);
        SBAR();
        asm volatile("s_waitcnt lgkmcnt(0)" ::: "memory");
        SBAR();
        __builtin_amdgcn_s_barrier();
        SBAR();
        #pragma unroll
        for (int ni = 0; ni < 2; ++ni) {
            const int nsw = (wc + ni * 16 + lr) ^ (g1 << 4);
            short8 b1 = bfrag(s1c, lk, nsw);
            short8 b3 = bfrag(s3c, lk, nsw);
            #pragma unroll
            for (int mi = 0; mi < 4; ++mi) {
                short8 a_ = __builtin_bit_cast(short8, af[mi]);
                acc1[mi][ni] = __builtin_amdgcn_mfma_f32_16x16x32_bf16(a_, b1, acc1[mi][ni], 0, 0, 0);
                acc3[mi][ni] = __builtin_amdgcn_mfma_f32_16x16x32_bf16(a_, b3, acc3[mi][ni], 0, 0, 0);
            }
        }
        SBAR();
        __builtin_amdgcn_s_barrier();
        SBAR();
    }
    #undef BLOAD1

    // ---- epilogue: h = relu(h1)*h3 -> bf16 compact rows
    const int hbase = offsets[e] + mt * 128;
    #pragma unroll
    for (int mi = 0; mi < 4; ++mi)
        #pragma unroll
        for (int ni = 0; ni < 2; ++ni)
            #pragma unroll
            for (int r = 0; r < 4; ++r) {
                int rl = wr + mi * 16 + (l >> 4) * 4 + r;
                int sl = mt * 128 + rl;
                if (sl < cnt) {
                    float v1 = acc1[mi][ni][r];
                    v1 = v1 > 0.f ? v1 : 0.f;
                    float hv = v1 * acc3[mi][ni][r];
                    hbuf[(size_t)(hbase + rl) * FDIM + (n0 + wc + ni * 16 + lr)] =
                        (u16)f2bf1(hv);
                }
            }
}

// ---------------------------------------------------------------- GEMM2
// out[t,n] += w * (h W2). BM=128 BN=64 BK=32, split-K x4. Same structure.
__global__ __launch_bounds__(256, 2)
void moe_gemm2(const u16* __restrict__ hbuf, const float* __restrict__ W2,
               const int* __restrict__ counts, const int* __restrict__ offsets,
               const int* __restrict__ tok_id, const float* __restrict__ tok_w,
               float* __restrict__ out) {
    const int nt = blockIdx.x, e = blockIdx.z;
    const int mt = blockIdx.y & 3, ksp = blockIdx.y >> 2;
    const int cnt = counts[e];
    if (mt * 128 >= cnt) return;
    const int n0 = nt * 64;
    const int tid = threadIdx.x;
    const int w = tid >> 6, l = tid & 63;

    __shared__ __align__(16) float sB[2][32 * 64];   // 16 KB

    const int wr = (w >> 1) * 64, wc = (w & 1) * 32;
    const int lr = l & 15, lg = l >> 4;
    const int lk = lg * 8;
    const int g1 = lg & 1;

    const u16* abase[4];
    #pragma unroll
    for (int mi = 0; mi < 4; ++mi) {
        int hrow = offsets[e] + mt * 128 + wr + mi * 16 + lr;  // tail rows stale, masked below
        abase[mi] = hbuf + (size_t)hrow * FDIM + ksp * 2048 + lk;
    }
    const int br = tid >> 3, bc = (tid & 7) * 8;
    const int bcx = bc ^ (((br >> 3) & 1) << 4);
    const float* b2s = W2 + (size_t)e * ((size_t)FDIM * HDIM) +
                       (size_t)(ksp * 2048 + br) * HDIM + n0 + bc;
    const int bldst = br * 64 + bcx;

    f32x4 acc[4][2];
    #pragma unroll
    for (int mi = 0; mi < 4; ++mi)
        #pragma unroll
        for (int ni = 0; ni < 2; ++ni) acc[mi][ni] = (f32x4)0.f;

    float4 r2a, r2b;
    uint4 af[4];

    #define BLOAD2(kt) { const float* p_ = b2s + (size_t)(kt) * 32 * HDIM;     \
                         r2a = *(const float4*)p_;                             \
                         r2b = *(const float4*)(p_ + 4); }

    BLOAD2(0);
    for (int kt = 0; kt < 64; ++kt) {
        float* sc = sB[kt & 1];
        *(float4*)&sc[bldst] = r2a;  *(float4*)&sc[bldst + 4] = r2b;
        SBAR();
        #pragma unroll
        for (int mi = 0; mi < 4; ++mi)
            af[mi] = *(const uint4*)(abase[mi] + (size_t)kt * 32);
        SBAR();
        if (kt + 1 < 64) BLOAD2(kt + 1);
        SBAR();
        asm volatile("s_waitcnt lgkmcnt(0)" ::: "memory");
        SBAR();
        __builtin_amdgcn_s_barrier();
        SBAR();
        #pragma unroll
        for (int ni = 0; ni < 2; ++ni) {
            const int nsw = (wc + ni * 16 + lr) ^ (g1 << 4);
            short8 b = bfrag(sc, lk, nsw);
            #pragma unroll
            for (int mi = 0; mi < 4; ++mi) {
                short8 a_ = __builtin_bit_cast(short8, af[mi]);
                acc[mi][ni] = __builtin_amdgcn_mfma_f32_16x16x32_bf16(a_, b, acc[mi][ni], 0, 0, 0);
            }
        }
        SBAR();
        __builtin_amdgcn_s_barrier();
        SBAR();
    }
    #undef BLOAD2

    // ---- epilogue: scaled partial scatter-add
    #pragma unroll
    for (int mi = 0; mi < 4; ++mi)
        #pragma unroll
        for (int ni = 0; ni < 2; ++ni)
            #pragma unroll
            for (int r = 0; r < 4; ++r) {
                int rl = wr + mi * 16 + (l >> 4) * 4 + r;
                int sl = mt * 128 + rl;
                if (sl < cnt) {
                    int tk = tok_id[e * MAXT + sl];
                    float wgt = tok_w[e * MAXT + sl];
                    atomicAdd(&out[(size_t)tk * HDIM + (n0 + wc + ni * 16 + lr)],
                              wgt * acc[mi][ni][r]);
                }
            }
}

// ---------------------------------------------------------------- launch
extern "C" void kernel_launch(void* const* d_in, const int* in_sizes, int n_in,
                              void* d_out, int out_size, void* d_ws, size_t ws_size,
                              hipStream_t stream) {
    const float* x  = (const float*)d_in[0];
    const float* Wg = (const float*)d_in[1];
    const float* W1 = (const float*)d_in[2];
    const float* W2 = (const float*)d_in[3];
    const float* W3 = (const float*)d_in[4];
    float* out = (float*)d_out;

    char* ws = (char*)d_ws;
    int*   counts  = (int*)(ws + 0);
    int*   offsets = (int*)(ws + 32);
    int*   tok_id  = (int*)(ws + 64);
    float* tok_w   = (float*)(ws + 64 + NEXP * MAXT * 4);
    u16*   xbf     = (u16*)(ws + 65536);                            // 512x2048 bf16 = 2MB
    u16*   hbuf    = (u16*)(ws + 65536 + (size_t)NTOK * HDIM * 2);  // (1024+128)x8192 bf16

    hipMemsetAsync(ws, 0, 64, stream);
    hipMemsetAsync(d_out, 0, (size_t)out_size * sizeof(float), stream);

    moe_router<<<NTOK, 64, 0, stream>>>(x, Wg, counts, tok_id, tok_w);
    moe_scan<<<1, 64, 0, stream>>>(counts, offsets);
    moe_xcvt<<<NTOK * HDIM / (256 * 8), 256, 0, stream>>>(x, xbf);
    moe_gemm1<<<dim3(FDIM / 64, 4, NEXP), 256, 0, stream>>>(xbf, W1, W3, counts, offsets, tok_id, hbuf);
    moe_gemm2<<<dim3(HDIM / 64, 16, NEXP), 256, 0, stream>>>(hbuf, W2, counts, offsets, tok_id, tok_w, out);
}